// Round 2
// baseline (1062.314 us; speedup 1.0000x reference)
//
#include <hip/hip_runtime.h>
#include <math.h>

#define N_RES  8192
#define N_IN   256
#define BATCH  16
#define NRANGE 4
#define RROWS  2048            // rows per range (NRANGE * RROWS == N_RES)
#define CHUNK  2048            // nnz staged per iteration
#define NSLICE 64              // nnz slices
#define TPB    512

// ---------------------------------------------------------------------------
// init: z_acc[r*16+b] = bias[r];  state_T[r*16+b] = state[b*N_RES+r];
//       x_T[c*16+b]   = x[b*N_IN+c]
// ---------------------------------------------------------------------------
__global__ void init_kernel(const float* __restrict__ state,
                            const float* __restrict__ x,
                            const float* __restrict__ bias,
                            float* __restrict__ z_acc,
                            float* __restrict__ state_T,
                            float* __restrict__ x_T) {
    int i = blockIdx.x * blockDim.x + threadIdx.x;
    if (i < N_RES * BATCH) {
        int r = i >> 4;
        int b = i & 15;
        state_T[i] = state[b * N_RES + r];
        z_acc[i]   = bias[r];
    }
    if (i < N_IN * BATCH) {
        int c = i >> 4;
        int b = i & 15;
        x_T[i] = x[b * N_IN + c];
    }
}

// ---------------------------------------------------------------------------
// accum: block = (slice, range). Stream slice's triples through LDS staging;
// accumulate rows in [rbase, rbase+RROWS) into a 128 KB LDS accumulator with
// ds_add_f32; flush once with coalesced 64B global atomics.
// ---------------------------------------------------------------------------
__global__ __launch_bounds__(TPB)
void accum_kernel(const float* __restrict__ res_vals,
                  const int*   __restrict__ res_rows,
                  const int*   __restrict__ res_cols,
                  const float* __restrict__ in_vals,
                  const int*   __restrict__ in_rows,
                  const int*   __restrict__ in_cols,
                  const float* __restrict__ state_T,   // [N_RES][16]
                  const float* __restrict__ x_T,       // [N_IN][16]
                  float* __restrict__ z_acc,           // [N_RES][16]
                  int nnz_res, int nnz_in) {
    __shared__ float zl[RROWS * BATCH];                 // 128 KB
    __shared__ __align__(16) float sv[CHUNK];           // 8 KB
    __shared__ __align__(16) int   sr[CHUNK];           // 8 KB
    __shared__ __align__(16) int   sc[CHUNK];           // 8 KB

    const int bid   = blockIdx.x;
    const int slice = bid >> 2;          // 0..63
    const int range = bid & (NRANGE - 1);
    const int rbase = range * RROWS;
    const int tid   = threadIdx.x;
    const int g     = tid >> 4;          // 0..31 (16-lane groups)
    const int lane  = tid & 15;          // batch element

    for (int i = tid; i < RROWS * BATCH; i += TPB) zl[i] = 0.0f;

    // ---- reservoir stream ----
    {
        int chunks_total = (nnz_res + CHUNK - 1) / CHUNK;
        int cps = (chunks_total + NSLICE - 1) / NSLICE;      // chunks per slice
        int s_begin = slice * cps * CHUNK;
        int s_end   = s_begin + cps * CHUNK;
        if (s_end > nnz_res) s_end = nnz_res;
        for (int chunk = s_begin; chunk < s_end; chunk += CHUNK) {
            int cnt = s_end - chunk; if (cnt > CHUNK) cnt = CHUNK;
            __syncthreads();   // staging reuse barrier (also covers zl init)
            if (cnt == CHUNK) {
                int i4 = tid << 2;
                *(float4*)&sv[i4] = *(const float4*)&res_vals[chunk + i4];
                *(int4*)  &sr[i4] = *(const int4*)  &res_rows[chunk + i4];
                *(int4*)  &sc[i4] = *(const int4*)  &res_cols[chunk + i4];
            } else {
                for (int i = tid; i < cnt; i += TPB) {
                    sv[i] = res_vals[chunk + i];
                    sr[i] = res_rows[chunk + i];
                    sc[i] = res_cols[chunk + i];
                }
            }
            __syncthreads();
            for (int i = g; i < cnt; i += 32) {
                unsigned d = (unsigned)(sr[i] - rbase);
                if (d < RROWS) {
                    float s = state_T[(sc[i] << 4) + lane];  // 64B coalesced gather
                    atomicAdd(&zl[(d << 4) + lane], sv[i] * s);
                }
            }
        }
    }

    // ---- input stream ----
    {
        int chunks_total = (nnz_in + CHUNK - 1) / CHUNK;
        int cps = (chunks_total + NSLICE - 1) / NSLICE;
        int s_begin = slice * cps * CHUNK;
        int s_end   = s_begin + cps * CHUNK;
        if (s_end > nnz_in) s_end = nnz_in;
        for (int chunk = s_begin; chunk < s_end; chunk += CHUNK) {
            int cnt = s_end - chunk; if (cnt > CHUNK) cnt = CHUNK;
            __syncthreads();
            if (cnt == CHUNK) {
                int i4 = tid << 2;
                *(float4*)&sv[i4] = *(const float4*)&in_vals[chunk + i4];
                *(int4*)  &sr[i4] = *(const int4*)  &in_rows[chunk + i4];
                *(int4*)  &sc[i4] = *(const int4*)  &in_cols[chunk + i4];
            } else {
                for (int i = tid; i < cnt; i += TPB) {
                    sv[i] = in_vals[chunk + i];
                    sr[i] = in_rows[chunk + i];
                    sc[i] = in_cols[chunk + i];
                }
            }
            __syncthreads();
            for (int i = g; i < cnt; i += 32) {
                unsigned d = (unsigned)(sr[i] - rbase);
                if (d < RROWS) {
                    float s = x_T[(sc[i] << 4) + lane];
                    atomicAdd(&zl[(d << 4) + lane], sv[i] * s);
                }
            }
        }
    }

    __syncthreads();

    // ---- flush: 2048 coalesced 64B atomic adds per block, start-row rotated
    // per slice so the 64 slice-blocks of a range don't hammer the same lines
    // simultaneously ----
    int rot = (slice * 32) & (RROWS - 1);
    for (int k = 0; k < RROWS / 32; ++k) {
        int r = (g + k * 32 + rot) & (RROWS - 1);
        unsafeAtomicAdd(&z_acc[((rbase + r) << 4) + lane], zl[(r << 4) + lane]);
    }
}

// ---------------------------------------------------------------------------
// finish: out[b*N_RES + r] = erf(z_acc[r*16 + b])   (A_LEAK == 1.0)
// ---------------------------------------------------------------------------
__global__ void finish_kernel(const float* __restrict__ z_acc,
                              float* __restrict__ out) {
    int i = blockIdx.x * blockDim.x + threadIdx.x;  // i = b*N_RES + r
    if (i < N_RES * BATCH) {
        int b = i >> 13;
        int r = i & (N_RES - 1);
        out[i] = erff(z_acc[(r << 4) + b]);
    }
}

extern "C" void kernel_launch(void* const* d_in, const int* in_sizes, int n_in,
                              void* d_out, int out_size, void* d_ws, size_t ws_size,
                              hipStream_t stream) {
    const float* state    = (const float*)d_in[0];
    const float* x        = (const float*)d_in[1];
    const float* res_vals = (const float*)d_in[2];
    const int*   res_rows = (const int*)  d_in[3];
    const int*   res_cols = (const int*)  d_in[4];
    const float* res_bias = (const float*)d_in[5];
    const float* in_vals  = (const float*)d_in[6];
    const int*   in_rows  = (const int*)  d_in[7];
    const int*   in_cols  = (const int*)  d_in[8];
    float* out = (float*)d_out;

    float* ws      = (float*)d_ws;
    float* z_acc   = ws;                       // N_RES*16 floats (512 KB)
    float* state_T = z_acc + N_RES * BATCH;    // N_RES*16 floats (512 KB)
    float* x_T     = state_T + N_RES * BATCH;  // N_IN*16  floats (16 KB)

    int nnz_res = in_sizes[2];
    int nnz_in  = in_sizes[6];

    init_kernel<<<(N_RES * BATCH + 255) / 256, 256, 0, stream>>>(
        state, x, res_bias, z_acc, state_T, x_T);

    accum_kernel<<<NSLICE * NRANGE, TPB, 0, stream>>>(
        res_vals, res_rows, res_cols, in_vals, in_rows, in_cols,
        state_T, x_T, z_acc, nnz_res, nnz_in);

    finish_kernel<<<(N_RES * BATCH + 255) / 256, 256, 0, stream>>>(z_acc, out);
}

// Round 3
// 715.771 us; speedup vs baseline: 1.4842x; 1.4842x over previous
//
#include <hip/hip_runtime.h>
#include <math.h>

#define N_RES 8192
#define N_IN  256
#define BATCH 16

// ---- binned-path parameters ----
#define NRANGE  16
#define RROWS   512                    // N_RES / NRANGE
#define CAP     475136                 // bucket capacity per range (mean ~432.5K)
#define P1_TPB  256
#define P1_ITER 8
#define P1_TILE (P1_TPB * P1_ITER)     // 2048
#define P1_GRID 1024
#define NSLICE2 32
#define P2_TPB  512

// ---------------------------------------------------------------------------
// init: z_acc[r*16+b] = bias[r]; state_T[r*16+b] = state[b*N_RES+r];
//       x_T[c*16+b] = x[b*N_IN+c]; zero bucket counters.
// ---------------------------------------------------------------------------
__global__ void init_kernel(const float* __restrict__ state,
                            const float* __restrict__ x,
                            const float* __restrict__ bias,
                            float* __restrict__ z_acc,
                            float* __restrict__ state_T,
                            float* __restrict__ x_T,
                            int* __restrict__ gcount) {
    int i = blockIdx.x * blockDim.x + threadIdx.x;
    if (i < N_RES * BATCH) {
        int r = i >> 4;
        int b = i & 15;
        state_T[i] = state[b * N_RES + r];
        z_acc[i]   = bias[r];
    }
    if (i < N_IN * BATCH) {
        int c = i >> 4;
        int b = i & 15;
        x_T[i] = x[b * N_IN + c];
    }
    if (i < NRANGE) gcount[i] = 0;
}

// ---------------------------------------------------------------------------
// phase 1: bin triples into per-row-range buckets of 8B entries
// {val, flag<<22 | d<<13 | col}. LDS histogram -> one global atomic per
// range per tile; LDS reorder stage so bucket writes are coalesced.
// ---------------------------------------------------------------------------
__global__ __launch_bounds__(P1_TPB)
void bin_kernel(const float* __restrict__ res_vals,
                const int*   __restrict__ res_rows,
                const int*   __restrict__ res_cols,
                const float* __restrict__ in_vals,
                const int*   __restrict__ in_rows,
                const int*   __restrict__ in_cols,
                float2* __restrict__ bucket,     // [NRANGE][CAP]
                int*    __restrict__ gcount,     // [NRANGE]
                int nnz_res, int nnz_total) {
    __shared__ int hcount[NRANGE];
    __shared__ int hbase[NRANGE];
    __shared__ int gbase[NRANGE];
    __shared__ float2 stage[P1_TILE];            // 16 KB

    const int tid = threadIdx.x;
    const int ntiles = (nnz_total + P1_TILE - 1) / P1_TILE;

    for (int tile = blockIdx.x; tile < ntiles; tile += gridDim.x) {
        const int base = tile * P1_TILE;
        if (tid < NRANGE) hcount[tid] = 0;
        __syncthreads();

        float    ev[P1_ITER];
        unsigned ep[P1_ITER];
        int      erg[P1_ITER];
        int      eslot[P1_ITER];
        #pragma unroll
        for (int j = 0; j < P1_ITER; ++j) {
            int idx = base + j * P1_TPB + tid;
            erg[j] = -1;
            if (idx < nnz_total) {
                float v; int r, c; unsigned flag;
                if (idx < nnz_res) {
                    v = res_vals[idx]; r = res_rows[idx]; c = res_cols[idx]; flag = 0u;
                } else {
                    int k = idx - nnz_res;
                    v = in_vals[k]; r = in_rows[k]; c = in_cols[k]; flag = 1u << 22;
                }
                int rg = r >> 9;                          // row range
                unsigned d = (unsigned)(r & (RROWS - 1)); // row within range
                ev[j] = v;
                ep[j] = flag | (d << 13) | (unsigned)c;
                erg[j] = rg;
                eslot[j] = atomicAdd(&hcount[rg], 1);
            }
        }
        __syncthreads();
        if (tid < NRANGE) gbase[tid] = atomicAdd(&gcount[tid], hcount[tid]);
        if (tid == 0) {
            int s = 0;
            #pragma unroll
            for (int r = 0; r < NRANGE; ++r) { hbase[r] = s; s += hcount[r]; }
        }
        __syncthreads();
        #pragma unroll
        for (int j = 0; j < P1_ITER; ++j)
            if (erg[j] >= 0)
                stage[hbase[erg[j]] + eslot[j]] = make_float2(ev[j], __uint_as_float(ep[j]));
        __syncthreads();

        const int tot = hbase[NRANGE - 1] + hcount[NRANGE - 1];
        for (int k = tid; k < tot; k += P1_TPB) {
            int lo = 0;  // binary search: largest r with hbase[r] <= k
            #pragma unroll
            for (int step = 8; step >= 1; step >>= 1) {
                int cand = lo + step;
                if (cand < NRANGE && hbase[cand] <= k) lo = cand;
            }
            int go = gbase[lo] + (k - hbase[lo]);
            if (go < CAP) bucket[(size_t)lo * CAP + go] = stage[k];
        }
        // next-tile hcount zeroing is safe: all threads must reach the next
        // __syncthreads() (which follows the zeroing) before stage reuse.
    }
}

// ---------------------------------------------------------------------------
// phase 2: block = (range, slice). Stream this slice of the range's bucket,
// accumulate into 32 KB LDS (ds_add_f32), flush with coalesced 64B atomics.
// 16-lane group per entry; lane = batch element. No barriers in the loop.
// ---------------------------------------------------------------------------
__device__ __forceinline__ void process_entry(float2 e, int lane,
                                              const float* __restrict__ state_T,
                                              const float* __restrict__ x_T,
                                              float* __restrict__ zl) {
    unsigned u = __float_as_uint(e.y);
    const float* sp = (u & (1u << 22)) ? x_T : state_T;
    float s = sp[(int)((u & 0x1FFFu) << 4) + lane];
    atomicAdd(&zl[(int)(((u >> 13) & 0x1FFu) << 4) + lane], e.x * s);
}

__global__ __launch_bounds__(P2_TPB)
void accum2_kernel(const float2* __restrict__ bucket,
                   const int*    __restrict__ gcount,
                   const float*  __restrict__ state_T,
                   const float*  __restrict__ x_T,
                   float* __restrict__ z_acc) {
    __shared__ float zl[RROWS * BATCH];           // 32 KB
    const int tid   = threadIdx.x;
    const int range = (int)blockIdx.x >> 5;       // / NSLICE2
    const int slice = (int)blockIdx.x & (NSLICE2 - 1);
    const int g     = tid >> 4;                   // 32 groups
    const int lane  = tid & 15;

    for (int i = tid; i < RROWS * BATCH; i += P2_TPB) zl[i] = 0.0f;
    __syncthreads();

    int cnt = gcount[range]; if (cnt > CAP) cnt = CAP;
    int per = (cnt + NSLICE2 - 1) / NSLICE2;
    int start = slice * per;
    int end = start + per; if (end > cnt) end = cnt;

    const float2* bk = bucket + (size_t)range * CAP;
    int k = start + g;
    for (; k + 96 < end; k += 128) {              // 4x unrolled, independent chains
        float2 e0 = bk[k];
        float2 e1 = bk[k + 32];
        float2 e2 = bk[k + 64];
        float2 e3 = bk[k + 96];
        process_entry(e0, lane, state_T, x_T, zl);
        process_entry(e1, lane, state_T, x_T, zl);
        process_entry(e2, lane, state_T, x_T, zl);
        process_entry(e3, lane, state_T, x_T, zl);
    }
    for (; k < end; k += 32) process_entry(bk[k], lane, state_T, x_T, zl);

    __syncthreads();

    // flush: 512 rows x 16 lanes, rotated per slice to spread line contention
    const int rot = (slice * 16) & (RROWS - 1);
    const int rbase = range * RROWS;
    #pragma unroll
    for (int kk = 0; kk < RROWS / 32; ++kk) {
        int r = (g + kk * 32 + rot) & (RROWS - 1);
        unsafeAtomicAdd(&z_acc[((rbase + r) << 4) + lane], zl[(r << 4) + lane]);
    }
}

// ---------------------------------------------------------------------------
// fallback (small ws): round-1 global-atomic scatter
// ---------------------------------------------------------------------------
__global__ void scatter_kernel(const float* __restrict__ vals,
                               const int* __restrict__ rows,
                               const int* __restrict__ cols,
                               const float* __restrict__ src_T,
                               float* __restrict__ z_acc,
                               int nnz) {
    int tid = blockIdx.x * blockDim.x + threadIdx.x;
    int g   = tid >> 4;
    int b   = tid & 15;
    int ngroups = (gridDim.x * blockDim.x) >> 4;
    for (int k = g; k < nnz; k += ngroups) {
        float v = vals[k];
        int   r = rows[k];
        int   c = cols[k];
        float s = src_T[(c << 4) + b];
        unsafeAtomicAdd(&z_acc[(r << 4) + b], v * s);
    }
}

// ---------------------------------------------------------------------------
// finish: out[b*N_RES + r] = erf(z_acc[r*16 + b])   (A_LEAK == 1.0)
// ---------------------------------------------------------------------------
__global__ void finish_kernel(const float* __restrict__ z_acc,
                              float* __restrict__ out) {
    int i = blockIdx.x * blockDim.x + threadIdx.x;
    if (i < N_RES * BATCH) {
        int b = i >> 13;
        int r = i & (N_RES - 1);
        out[i] = erff(z_acc[(r << 4) + b]);
    }
}

extern "C" void kernel_launch(void* const* d_in, const int* in_sizes, int n_in,
                              void* d_out, int out_size, void* d_ws, size_t ws_size,
                              hipStream_t stream) {
    const float* state    = (const float*)d_in[0];
    const float* x        = (const float*)d_in[1];
    const float* res_vals = (const float*)d_in[2];
    const int*   res_rows = (const int*)  d_in[3];
    const int*   res_cols = (const int*)  d_in[4];
    const float* res_bias = (const float*)d_in[5];
    const float* in_vals  = (const float*)d_in[6];
    const int*   in_rows  = (const int*)  d_in[7];
    const int*   in_cols  = (const int*)  d_in[8];
    float* out = (float*)d_out;

    float* ws      = (float*)d_ws;
    float* z_acc   = ws;                        // 131072 f (512 KB)
    float* state_T = z_acc + N_RES * BATCH;     // 131072 f (512 KB)
    float* x_T     = state_T + N_RES * BATCH;   // 4096 f (16 KB)
    int*   gcount  = (int*)(x_T + N_IN * BATCH);// 16 ints
    float2* bucket = (float2*)(gcount + 16);    // NRANGE*CAP entries

    const size_t required = (size_t)(N_RES * BATCH * 2 + N_IN * BATCH + 16) * 4
                          + (size_t)NRANGE * CAP * sizeof(float2);

    int nnz_res = in_sizes[2];
    int nnz_in  = in_sizes[6];

    init_kernel<<<(N_RES * BATCH + 255) / 256, 256, 0, stream>>>(
        state, x, res_bias, z_acc, state_T, x_T, gcount);

    if (ws_size >= required) {
        bin_kernel<<<P1_GRID, P1_TPB, 0, stream>>>(
            res_vals, res_rows, res_cols, in_vals, in_rows, in_cols,
            bucket, gcount, nnz_res, nnz_res + nnz_in);
        accum2_kernel<<<NRANGE * NSLICE2, P2_TPB, 0, stream>>>(
            bucket, gcount, state_T, x_T, z_acc);
    } else {
        scatter_kernel<<<2048, 256, 0, stream>>>(
            res_vals, res_rows, res_cols, state_T, z_acc, nnz_res);
        scatter_kernel<<<512, 256, 0, stream>>>(
            in_vals, in_rows, in_cols, x_T, z_acc, nnz_in);
    }

    finish_kernel<<<(N_RES * BATCH + 255) / 256, 256, 0, stream>>>(z_acc, out);
}

// Round 4
// 708.259 us; speedup vs baseline: 1.4999x; 1.0106x over previous
//
#include <hip/hip_runtime.h>
#include <math.h>

#define N_RES 8192
#define N_IN  256
#define BATCH 16

// ---- binned-path parameters ----
#define NRANGE  16
#define RROWS   512                    // N_RES / NRANGE
#define CAP     475136                 // bucket capacity per range (mean ~432.5K, +66 sigma)
#define P1_TPB  256
#define P1_ITER 16
#define P1_TILE (P1_TPB * P1_ITER)     // 4096
#define P1_GRID 1024
#define NSLICE2 64
#define P2_TPB  512

// raw LDS float atomic add: ds_add_f32 (no return, no CAS loop).
// LDS byte offset = low 32 bits of the generic pointer (shared-aperture layout).
__device__ __forceinline__ void lds_fadd(float* p, float v) {
    unsigned a = (unsigned)(uintptr_t)p;
    asm volatile("ds_add_f32 %0, %1" : : "v"(a), "v"(v));
}

// ---------------------------------------------------------------------------
// init
// ---------------------------------------------------------------------------
__global__ void init_kernel(const float* __restrict__ state,
                            const float* __restrict__ x,
                            const float* __restrict__ bias,
                            float* __restrict__ z_acc,
                            float* __restrict__ state_T,
                            float* __restrict__ x_T,
                            int* __restrict__ gcount) {
    int i = blockIdx.x * blockDim.x + threadIdx.x;
    if (i < N_RES * BATCH) {
        int r = i >> 4;
        int b = i & 15;
        state_T[i] = state[b * N_RES + r];
        z_acc[i]   = bias[r];
    }
    if (i < N_IN * BATCH) {
        int c = i >> 4;
        int b = i & 15;
        x_T[i] = x[b * N_IN + c];
    }
    if (i < NRANGE) gcount[i] = 0;
}

// ---------------------------------------------------------------------------
// phase 1: bin triples into per-row-range buckets of 8B entries
// {val, flag<<22 | d<<13 | col}. LDS histogram + LDS reorder -> coalesced
// bucket writes.
// ---------------------------------------------------------------------------
__global__ __launch_bounds__(P1_TPB)
void bin_kernel(const float* __restrict__ res_vals,
                const int*   __restrict__ res_rows,
                const int*   __restrict__ res_cols,
                const float* __restrict__ in_vals,
                const int*   __restrict__ in_rows,
                const int*   __restrict__ in_cols,
                float2* __restrict__ bucket,     // [NRANGE][CAP]
                int*    __restrict__ gcount,     // [NRANGE]
                int nnz_res, int nnz_total) {
    __shared__ int hcount[NRANGE];
    __shared__ int hbase[NRANGE];
    __shared__ int gbase[NRANGE];
    __shared__ float2 stage[P1_TILE];            // 32 KB

    const int tid = threadIdx.x;
    const int ntiles = (nnz_total + P1_TILE - 1) / P1_TILE;

    for (int tile = blockIdx.x; tile < ntiles; tile += gridDim.x) {
        const int base = tile * P1_TILE;
        if (tid < NRANGE) hcount[tid] = 0;
        __syncthreads();

        float    ev[P1_ITER];
        unsigned ep[P1_ITER];
        int      erg[P1_ITER];
        int      eslot[P1_ITER];
        #pragma unroll
        for (int j = 0; j < P1_ITER; ++j) {
            int idx = base + j * P1_TPB + tid;
            erg[j] = -1;
            if (idx < nnz_total) {
                float v; int r, c; unsigned flag;
                if (idx < nnz_res) {
                    v = res_vals[idx]; r = res_rows[idx]; c = res_cols[idx]; flag = 0u;
                } else {
                    int k = idx - nnz_res;
                    v = in_vals[k]; r = in_rows[k]; c = in_cols[k]; flag = 1u << 22;
                }
                int rg = r >> 9;                          // row range
                unsigned d = (unsigned)(r & (RROWS - 1)); // row within range
                ev[j] = v;
                ep[j] = flag | (d << 13) | (unsigned)c;
                erg[j] = rg;
                eslot[j] = atomicAdd(&hcount[rg], 1);     // int LDS atomic: native
            }
        }
        __syncthreads();
        if (tid < NRANGE) gbase[tid] = atomicAdd(&gcount[tid], hcount[tid]);
        if (tid == 0) {
            int s = 0;
            #pragma unroll
            for (int r = 0; r < NRANGE; ++r) { hbase[r] = s; s += hcount[r]; }
        }
        __syncthreads();
        #pragma unroll
        for (int j = 0; j < P1_ITER; ++j)
            if (erg[j] >= 0)
                stage[hbase[erg[j]] + eslot[j]] = make_float2(ev[j], __uint_as_float(ep[j]));
        __syncthreads();

        const int tot = hbase[NRANGE - 1] + hcount[NRANGE - 1];
        for (int k = tid; k < tot; k += P1_TPB) {
            int lo = 0;  // binary search: largest r with hbase[r] <= k
            #pragma unroll
            for (int step = 8; step >= 1; step >>= 1) {
                int cand = lo + step;
                if (cand < NRANGE && hbase[cand] <= k) lo = cand;
            }
            int go = gbase[lo] + (k - hbase[lo]);
            if (go < CAP) bucket[(size_t)lo * CAP + go] = stage[k];
        }
    }
}

// ---------------------------------------------------------------------------
// phase 2: block = (range, slice). Stream slice of the range's bucket,
// accumulate into 32 KB LDS with raw ds_add_f32, flush with coalesced 64B
// global atomics. 16-lane group per entry; lane = batch element.
// ---------------------------------------------------------------------------
__device__ __forceinline__ void process_entry(float2 e, int lane,
                                              const float* __restrict__ state_T,
                                              const float* __restrict__ x_T,
                                              float* __restrict__ zl) {
    unsigned u = __float_as_uint(e.y);
    const float* sp = (u & (1u << 22)) ? x_T : state_T;
    float s = sp[(int)((u & 0x1FFFu) << 4) + lane];
    lds_fadd(&zl[(int)(((u >> 13) & 0x1FFu) << 4) + lane], e.x * s);
}

__global__ __launch_bounds__(P2_TPB)
void accum2_kernel(const float2* __restrict__ bucket,
                   const int*    __restrict__ gcount,
                   const float*  __restrict__ state_T,
                   const float*  __restrict__ x_T,
                   float* __restrict__ z_acc) {
    __shared__ float zl[RROWS * BATCH];           // 32 KB
    const int tid   = threadIdx.x;
    const int range = (int)blockIdx.x >> 6;       // / NSLICE2
    const int slice = (int)blockIdx.x & (NSLICE2 - 1);
    const int g     = tid >> 4;                   // 32 groups
    const int lane  = tid & 15;

    for (int i = tid; i < RROWS * BATCH; i += P2_TPB) zl[i] = 0.0f;
    __syncthreads();

    int cnt = gcount[range]; if (cnt > CAP) cnt = CAP;
    int per = (cnt + NSLICE2 - 1) / NSLICE2;
    int start = slice * per;
    int end = start + per; if (end > cnt) end = cnt;

    const float2* bk = bucket + (size_t)range * CAP;
    int k = start + g;
    for (; k + 224 < end; k += 256) {             // 8 independent chains
        float2 e0 = bk[k];
        float2 e1 = bk[k + 32];
        float2 e2 = bk[k + 64];
        float2 e3 = bk[k + 96];
        float2 e4 = bk[k + 128];
        float2 e5 = bk[k + 160];
        float2 e6 = bk[k + 192];
        float2 e7 = bk[k + 224];
        process_entry(e0, lane, state_T, x_T, zl);
        process_entry(e1, lane, state_T, x_T, zl);
        process_entry(e2, lane, state_T, x_T, zl);
        process_entry(e3, lane, state_T, x_T, zl);
        process_entry(e4, lane, state_T, x_T, zl);
        process_entry(e5, lane, state_T, x_T, zl);
        process_entry(e6, lane, state_T, x_T, zl);
        process_entry(e7, lane, state_T, x_T, zl);
    }
    for (; k < end; k += 32) process_entry(bk[k], lane, state_T, x_T, zl);

    // drain asm-issued ds_add_f32 ops (compiler doesn't track them)
    asm volatile("s_waitcnt lgkmcnt(0)");
    __syncthreads();

    // flush: 512 rows x 16 lanes, rotated per slice to spread line contention
    const int rot = (slice * 8) & (RROWS - 1);
    const int rbase = range * RROWS;
    #pragma unroll
    for (int kk = 0; kk < RROWS / 32; ++kk) {
        int r = (g + kk * 32 + rot) & (RROWS - 1);
        unsafeAtomicAdd(&z_acc[((rbase + r) << 4) + lane], zl[(r << 4) + lane]);
    }
}

// ---------------------------------------------------------------------------
// fallback (small ws): round-1 global-atomic scatter
// ---------------------------------------------------------------------------
__global__ void scatter_kernel(const float* __restrict__ vals,
                               const int* __restrict__ rows,
                               const int* __restrict__ cols,
                               const float* __restrict__ src_T,
                               float* __restrict__ z_acc,
                               int nnz) {
    int tid = blockIdx.x * blockDim.x + threadIdx.x;
    int g   = tid >> 4;
    int b   = tid & 15;
    int ngroups = (gridDim.x * blockDim.x) >> 4;
    for (int k = g; k < nnz; k += ngroups) {
        float v = vals[k];
        int   r = rows[k];
        int   c = cols[k];
        float s = src_T[(c << 4) + b];
        unsafeAtomicAdd(&z_acc[(r << 4) + b], v * s);
    }
}

// ---------------------------------------------------------------------------
// finish: out[b*N_RES + r] = erf(z_acc[r*16 + b])   (A_LEAK == 1.0)
// ---------------------------------------------------------------------------
__global__ void finish_kernel(const float* __restrict__ z_acc,
                              float* __restrict__ out) {
    int i = blockIdx.x * blockDim.x + threadIdx.x;
    if (i < N_RES * BATCH) {
        int b = i >> 13;
        int r = i & (N_RES - 1);
        out[i] = erff(z_acc[(r << 4) + b]);
    }
}

extern "C" void kernel_launch(void* const* d_in, const int* in_sizes, int n_in,
                              void* d_out, int out_size, void* d_ws, size_t ws_size,
                              hipStream_t stream) {
    const float* state    = (const float*)d_in[0];
    const float* x        = (const float*)d_in[1];
    const float* res_vals = (const float*)d_in[2];
    const int*   res_rows = (const int*)  d_in[3];
    const int*   res_cols = (const int*)  d_in[4];
    const float* res_bias = (const float*)d_in[5];
    const float* in_vals  = (const float*)d_in[6];
    const int*   in_rows  = (const int*)  d_in[7];
    const int*   in_cols  = (const int*)  d_in[8];
    float* out = (float*)d_out;

    float* ws      = (float*)d_ws;
    float* z_acc   = ws;                        // 131072 f (512 KB)
    float* state_T = z_acc + N_RES * BATCH;     // 131072 f (512 KB)
    float* x_T     = state_T + N_RES * BATCH;   // 4096 f (16 KB)
    int*   gcount  = (int*)(x_T + N_IN * BATCH);// 16 ints
    float2* bucket = (float2*)(gcount + 16);    // NRANGE*CAP entries

    const size_t required = (size_t)(N_RES * BATCH * 2 + N_IN * BATCH + 16) * 4
                          + (size_t)NRANGE * CAP * sizeof(float2);

    int nnz_res = in_sizes[2];
    int nnz_in  = in_sizes[6];

    init_kernel<<<(N_RES * BATCH + 255) / 256, 256, 0, stream>>>(
        state, x, res_bias, z_acc, state_T, x_T, gcount);

    if (ws_size >= required) {
        bin_kernel<<<P1_GRID, P1_TPB, 0, stream>>>(
            res_vals, res_rows, res_cols, in_vals, in_rows, in_cols,
            bucket, gcount, nnz_res, nnz_res + nnz_in);
        accum2_kernel<<<NRANGE * NSLICE2, P2_TPB, 0, stream>>>(
            bucket, gcount, state_T, x_T, z_acc);
    } else {
        scatter_kernel<<<2048, 256, 0, stream>>>(
            res_vals, res_rows, res_cols, state_T, z_acc, nnz_res);
        scatter_kernel<<<512, 256, 0, stream>>>(
            in_vals, in_rows, in_cols, x_T, z_acc, nnz_in);
    }

    finish_kernel<<<(N_RES * BATCH + 255) / 256, 256, 0, stream>>>(z_acc, out);
}